// Round 4
// baseline (166.818 us; speedup 1.0000x reference)
//
#include <hip/hip_runtime.h>
#include <hip/hip_bf16.h>
#include <math.h>

#define B_ 16
#define A_ 256
#define N_ 64
#define G_ 64
#define F_ 128

typedef __attribute__((ext_vector_type(8))) short short8;
typedef __attribute__((ext_vector_type(4))) float floatx4;

__device__ __forceinline__ float ssp(float x) {
    // shifted softplus via native v_exp_f32 / v_log_f32
    const float t = __expf(-fabsf(x));
    return fmaxf(x, 0.0f) + __logf(1.0f + t) - 0.69314718055994531f;
}
// branch-free RNE fp32->bf16 (finite inputs only) — 3 VALU ops
__device__ __forceinline__ unsigned short f2bf(float f) {
    union { float f; unsigned u; } v; v.f = f;
    v.u += 0x7fffu + ((v.u >> 16) & 1u);
    return (unsigned short)(v.u >> 16);
}
__device__ __forceinline__ float bf2f(unsigned short u) {
    union { unsigned i; float f; } v;
    v.i = ((unsigned)u) << 16;
    return v.f;
}

// ---------------------------------------------------------------------------
// K1: blocks [0,256): ypre = bf16(x @ w_in2f) via MFMA, 16 rows/block.
//     blocks [256,296): repack fw1/fw2/w_f2out into MFMA B-frag order.
// B-frag layout [tf][ks][lane(64)][j(8)]: k = ks*32+(lane>>4)*8+j, f = tf*16+(lane&15)
__global__ __launch_bounds__(256) void k1_prep_in2f(
    const float* __restrict__ x,   const float* __restrict__ win,
    const float* __restrict__ fw1, const float* __restrict__ fw2,
    const float* __restrict__ wout,
    unsigned short* __restrict__ ypre,
    unsigned short* __restrict__ fw1B, unsigned short* __restrict__ fw2B,
    unsigned short* __restrict__ woutB)
{
    const int bid = blockIdx.x;
    const int tid = threadIdx.x;

    if (bid >= 256) {   // ---- weight repack: 40 blocks x 1024 elems ----
        int idx = (bid - 256) * 1024 + tid * 4;
        #pragma unroll
        for (int u = 0; u < 4; ++u, ++idx) {
            if (idx < 8192) {                       // fw1: K=64
                const int j  = idx & 7;
                const int l  = (idx >> 3) & 63;
                const int ks = (idx >> 9) & 1;
                const int tf = idx >> 10;
                const int g  = ks * 32 + (l >> 4) * 8 + j;
                const int f  = tf * 16 + (l & 15);
                fw1B[idx] = f2bf(fw1[g * F_ + f]);
            } else {                                // fw2 / wout: K=128
                const int i2 = (idx - 8192) & 16383;
                const int sel = (idx - 8192) >> 14; // 0: fw2, 1: wout
                const int j  = i2 & 7;
                const int l  = (i2 >> 3) & 63;
                const int ks = (i2 >> 9) & 3;
                const int tf = i2 >> 11;
                const int k  = ks * 32 + (l >> 4) * 8 + j;
                const int f  = tf * 16 + (l & 15);
                if (sel == 0) fw2B[i2]  = f2bf(fw2[k * F_ + f]);
                else          woutB[i2] = f2bf(wout[k * F_ + f]);
            }
        }
        return;
    }

    // ---- in2f: 16 rows of ypre per block ----
    __shared__ unsigned short s_wt[128 * 136];   // win^T bf16, [f][k], pad 8

    const float4* win4 = (const float4*)win;
    for (int i = tid; i < 4096; i += 256) {
        const float4 v = win4[i];
        const int e = i * 4;
        const int k = e >> 7;
        const int f = e & 127;        // e%4==0 -> f..f+3 same k
        s_wt[(f + 0) * 136 + k] = f2bf(v.x);
        s_wt[(f + 1) * 136 + k] = f2bf(v.y);
        s_wt[(f + 2) * 136 + k] = f2bf(v.z);
        s_wt[(f + 3) * 136 + k] = f2bf(v.w);
    }
    __syncthreads();

    const int w = tid >> 6, l = tid & 63, quad = l >> 4, c0 = l & 15;
    const int row0 = bid * 16;

    short8 a[4];
    {
        const float* base = x + (size_t)(row0 + c0) * F_ + quad * 8;
        #pragma unroll
        for (int ks = 0; ks < 4; ++ks) {
            const float4 v0 = *(const float4*)(base + ks * 32);
            const float4 v1 = *(const float4*)(base + ks * 32 + 4);
            short8 t;
            t[0] = f2bf(v0.x); t[1] = f2bf(v0.y);
            t[2] = f2bf(v0.z); t[3] = f2bf(v0.w);
            t[4] = f2bf(v1.x); t[5] = f2bf(v1.y);
            t[6] = f2bf(v1.z); t[7] = f2bf(v1.w);
            a[ks] = t;
        }
    }

    floatx4 acc[2];
    acc[0] = (floatx4){0.f,0.f,0.f,0.f};
    acc[1] = (floatx4){0.f,0.f,0.f,0.f};
    #pragma unroll
    for (int t = 0; t < 2; ++t) {
        const int tf = w * 2 + t;
        #pragma unroll
        for (int ks = 0; ks < 4; ++ks) {
            const short8 bfrag = *(const short8*)
                &s_wt[(tf * 16 + c0) * 136 + ks * 32 + quad * 8];
            acc[t] = __builtin_amdgcn_mfma_f32_16x16x32_bf16(
                a[ks], bfrag, acc[t], 0, 0, 0);
        }
    }
    #pragma unroll
    for (int t = 0; t < 2; ++t) {
        const int tf = w * 2 + t;
        #pragma unroll
        for (int r = 0; r < 4; ++r)
            ypre[(size_t)(row0 + quad * 4 + r) * F_ + tf * 16 + c0] =
                f2bf(acc[t][r]);
    }
}

// ---------------------------------------------------------------------------
// K2: one block per (b,a). Filter net + cutoff + gather + aggregate + fused
// f2out (MFMA with y broadcast into all 16 A-rows -> every D-row valid).
__global__ __launch_bounds__(256) void cfconv_kernel(
    const float* __restrict__ r_ij, const float* __restrict__ f_ij,
    const int*   __restrict__ nbrs, const float* __restrict__ mask,
    const float* __restrict__ fb1,  const float* __restrict__ fb2,
    const unsigned short* __restrict__ ypre,
    const unsigned short* __restrict__ fw1B,
    const unsigned short* __restrict__ fw2B,
    const unsigned short* __restrict__ woutB,
    const float* __restrict__ bf2out,
    float* __restrict__ out)
{
    __shared__ short s_h1[N_ * F_];       // 16 KB, XOR-chunk swizzle
    __shared__ float s_scale[N_];
    __shared__ int   s_nb[N_];
    __shared__ float s_red[4][F_];
    __shared__ unsigned short s_yfb[F_];  // aggregated y, bf16, k-contiguous

    const int blk  = blockIdx.x;
    const int tid  = threadIdx.x;
    const int b    = blk >> 8;
    const int w    = tid >> 6;
    const int l    = tid & 63;
    const int quad = l >> 4;
    const int c0   = l & 15;

    if (l < 16) {
        const int n = w * 16 + l;
        const float r = r_ij[(size_t)blk * N_ + n];
        const float c = (r < 5.0f)
            ? 0.5f * (__cosf(r * 0.62831853071795865f) + 1.0f)
            : 0.0f;
        s_scale[n] = c * mask[(size_t)blk * N_ + n];
        s_nb[n]    = nbrs[(size_t)blk * N_ + n];
    }

    const short8* fw1B8  = (const short8*)fw1B;
    const short8* fw2B8  = (const short8*)fw2B;
    const short8* woutB8 = (const short8*)woutB;

    // ---- GEMM1: h1 = ssp(f_ij @ fw1 + fb1) ----
    short8 a1[2];
    {
        const float* base = f_ij + (size_t)blk * (N_ * G_)
                          + (size_t)(w * 16 + c0) * G_ + quad * 8;
        #pragma unroll
        for (int ks = 0; ks < 2; ++ks) {
            const float4 v0 = *(const float4*)(base + ks * 32);
            const float4 v1 = *(const float4*)(base + ks * 32 + 4);
            short8 a;
            a[0] = f2bf(v0.x); a[1] = f2bf(v0.y);
            a[2] = f2bf(v0.z); a[3] = f2bf(v0.w);
            a[4] = f2bf(v1.x); a[5] = f2bf(v1.y);
            a[6] = f2bf(v1.z); a[7] = f2bf(v1.w);
            a1[ks] = a;
        }
    }
    floatx4 acc1[8];
    #pragma unroll
    for (int tf = 0; tf < 8; ++tf) acc1[tf] = (floatx4){0.f,0.f,0.f,0.f};
    #pragma unroll
    for (int ks = 0; ks < 2; ++ks)
        #pragma unroll
        for (int tf = 0; tf < 8; ++tf)
            acc1[tf] = __builtin_amdgcn_mfma_f32_16x16x32_bf16(
                a1[ks], fw1B8[(tf * 2 + ks) * 64 + l], acc1[tf], 0, 0, 0);

    #pragma unroll
    for (int tf = 0; tf < 8; ++tf) {
        const float bias  = fb1[tf * 16 + c0];
        const int   chunk = tf * 2 + (c0 >> 3);
        const int   o     = c0 & 7;
        #pragma unroll
        for (int r = 0; r < 4; ++r) {
            const int row_l = quad * 4 + r;
            const float v = ssp(acc1[tf][r] + bias);
            s_h1[(w * 16 + row_l) * F_ + ((chunk ^ row_l) * 8) + o] =
                (short)f2bf(v);
        }
    }

    // ---- GEMM2 A-frags from LDS + prefetch gather rows ----
    short8 a2[4];
    #pragma unroll
    for (int ks = 0; ks < 4; ++ks)
        a2[ks] = *(const short8*)&s_h1[(w * 16 + c0) * F_
                                       + (((ks * 4 + quad) ^ c0) * 8)];

    int   rowoff[4];
    float scl[4];
    #pragma unroll
    for (int r = 0; r < 4; ++r) {
        const int n = w * 16 + quad * 4 + r;
        scl[r]    = s_scale[n];
        rowoff[r] = (b * A_ + s_nb[n]) * F_;
    }
    unsigned short yv[4][8];
    #pragma unroll
    for (int r = 0; r < 4; ++r)
        #pragma unroll
        for (int tf = 0; tf < 8; ++tf)
            yv[r][tf] = ypre[rowoff[r] + tf * 16 + c0];

    floatx4 acc2[8];
    #pragma unroll
    for (int tf = 0; tf < 8; ++tf) acc2[tf] = (floatx4){0.f,0.f,0.f,0.f};
    #pragma unroll
    for (int ks = 0; ks < 4; ++ks)
        #pragma unroll
        for (int tf = 0; tf < 8; ++tf)
            acc2[tf] = __builtin_amdgcn_mfma_f32_16x16x32_bf16(
                a2[ks], fw2B8[(tf * 4 + ks) * 64 + l], acc2[tf], 0, 0, 0);

    // ---- aggregate ----
    float part[8];
    #pragma unroll
    for (int tf = 0; tf < 8; ++tf) part[tf] = 0.0f;
    #pragma unroll
    for (int r = 0; r < 4; ++r)
        #pragma unroll
        for (int tf = 0; tf < 8; ++tf)
            part[tf] = fmaf((acc2[tf][r] + fb2[tf * 16 + c0]) * scl[r],
                            bf2f(yv[r][tf]), part[tf]);

    #pragma unroll
    for (int tf = 0; tf < 8; ++tf) {
        part[tf] += __shfl_xor(part[tf], 16, 64);
        part[tf] += __shfl_xor(part[tf], 32, 64);
    }
    if (l < 16) {
        #pragma unroll
        for (int tf = 0; tf < 8; ++tf)
            s_red[w][tf * 16 + l] = part[tf];
    }
    __syncthreads();

    if (tid < F_) {
        const float v = s_red[0][tid] + s_red[1][tid]
                      + s_red[2][tid] + s_red[3][tid];
        s_yfb[tid] = f2bf(v);
    }
    __syncthreads();

    // ---- fused f2out: broadcast y into all A-rows; wave w -> tf {2w,2w+1} ----
    short8 ya[4];
    #pragma unroll
    for (int ks = 0; ks < 4; ++ks)
        ya[ks] = *(const short8*)&s_yfb[ks * 32 + quad * 8];  // quad-broadcast

    floatx4 aco[2];
    aco[0] = (floatx4){0.f,0.f,0.f,0.f};
    aco[1] = (floatx4){0.f,0.f,0.f,0.f};
    #pragma unroll
    for (int t = 0; t < 2; ++t) {
        const int tf = w * 2 + t;
        #pragma unroll
        for (int ks = 0; ks < 4; ++ks)
            aco[t] = __builtin_amdgcn_mfma_f32_16x16x32_bf16(
                ya[ks], woutB8[(tf * 4 + ks) * 64 + l], aco[t], 0, 0, 0);
    }
    if (quad == 0) {
        #pragma unroll
        for (int t = 0; t < 2; ++t) {
            const int c = (w * 2 + t) * 16 + c0;
            out[(size_t)blk * F_ + c] = ssp(aco[t][0] + bf2out[c]);
        }
    }
}

// ---------------------------------------------------------------------------
extern "C" void kernel_launch(void* const* d_in, const int* in_sizes, int n_in,
                              void* d_out, int out_size, void* d_ws, size_t ws_size,
                              hipStream_t stream) {
    const float* x        = (const float*)d_in[0];
    const float* r_ij     = (const float*)d_in[1];
    const float* f_ij     = (const float*)d_in[2];
    const int*   nbrs     = (const int*)  d_in[3];
    const float* mask     = (const float*)d_in[4];
    const float* fw1      = (const float*)d_in[5];
    const float* fb1      = (const float*)d_in[6];
    const float* fw2      = (const float*)d_in[7];
    const float* fb2      = (const float*)d_in[8];
    const float* w_in2f   = (const float*)d_in[9];
    const float* w_f2out  = (const float*)d_in[10];
    const float* b_f2out  = (const float*)d_in[11];
    float* out = (float*)d_out;

    // ws (shorts): ypre | fw1B | fw2B | woutB
    unsigned short* ypre  = (unsigned short*)d_ws;
    unsigned short* fw1B  = ypre  + (size_t)B_ * A_ * F_;   // 524288
    unsigned short* fw2B  = fw1B  + 8192;
    unsigned short* woutB = fw2B  + 16384;

    k1_prep_in2f<<<296, 256, 0, stream>>>(
        x, w_in2f, fw1, fw2, w_f2out, ypre, fw1B, fw2B, woutB);
    cfconv_kernel<<<B_ * A_, 256, 0, stream>>>(
        r_ij, f_ij, nbrs, mask, fb1, fb2,
        ypre, fw1B, fw2B, woutB, b_f2out, out);
}

// Round 6
// 164.097 us; speedup vs baseline: 1.0166x; 1.0166x over previous
//
#include <hip/hip_runtime.h>
#include <hip/hip_bf16.h>
#include <math.h>

#define B_ 16
#define A_ 256
#define N_ 64
#define G_ 64
#define F_ 128

typedef __attribute__((ext_vector_type(8))) short short8;
typedef __attribute__((ext_vector_type(4))) float floatx4;

__device__ __forceinline__ float ssp(float x) {
    // shifted softplus via native v_exp_f32 / v_log_f32:
    // ln(1+e^x) - ln2 = max(x,0) + ln(1+e^-|x|) - ln2
    const float t = __expf(-fabsf(x));
    return fmaxf(x, 0.0f) + __logf(1.0f + t) - 0.69314718055994531f;
}
// branch-free RNE fp32->bf16 (finite inputs only)
__device__ __forceinline__ unsigned f2bf(float f) {
    union { float f; unsigned u; } v; v.f = f;
    v.u += 0x7fffu + ((v.u >> 16) & 1u);
    return v.u >> 16;
}
__device__ __forceinline__ float bf2f_lo(unsigned d) {
    union { unsigned i; float f; } v; v.i = d << 16; return v.f;
}
__device__ __forceinline__ float bf2f_hi(unsigned d) {
    union { unsigned i; float f; } v; v.i = d & 0xffff0000u; return v.f;
}

// ---------------------------------------------------------------------------
// K1: blocks [0,256): ypre = bf16(x @ w_in2f), PERMUTED layout
//       ypre[a*128 + c0*8 + tf], c0 = col&15, tf = col>>4.
//     blocks [256,296): repack fw1/fw2/w_f2out into MFMA B-frag order.
// B-frag layout [tf][ks][lane(64)][j(8)]: k = ks*32+(lane>>4)*8+j, f = tf*16+(lane&15)
__global__ __launch_bounds__(256) void k1_prep_in2f(
    const float* __restrict__ x,   const float* __restrict__ win,
    const float* __restrict__ fw1, const float* __restrict__ fw2,
    const float* __restrict__ wout,
    unsigned short* __restrict__ ypre,
    unsigned short* __restrict__ fw1B, unsigned short* __restrict__ fw2B,
    unsigned short* __restrict__ woutB)
{
    const int bid = blockIdx.x;
    const int tid = threadIdx.x;

    if (bid >= 256) {   // ---- weight repack ----
        int idx = (bid - 256) * 1024 + tid * 4;
        #pragma unroll
        for (int u = 0; u < 4; ++u, ++idx) {
            if (idx < 8192) {                       // fw1: K=64
                const int j  = idx & 7;
                const int l  = (idx >> 3) & 63;
                const int ks = (idx >> 9) & 1;
                const int tf = idx >> 10;
                const int g  = ks * 32 + (l >> 4) * 8 + j;
                const int f  = tf * 16 + (l & 15);
                fw1B[idx] = (unsigned short)f2bf(fw1[g * F_ + f]);
            } else {                                // fw2 / wout: K=128
                const int i2 = (idx - 8192) & 16383;
                const int sel = (idx - 8192) >> 14; // 0: fw2, 1: wout
                const int j  = i2 & 7;
                const int l  = (i2 >> 3) & 63;
                const int ks = (i2 >> 9) & 3;
                const int tf = i2 >> 11;
                const int k  = ks * 32 + (l >> 4) * 8 + j;
                const int f  = tf * 16 + (l & 15);
                if (sel == 0) fw2B[i2]  = (unsigned short)f2bf(fw2[k * F_ + f]);
                else          woutB[i2] = (unsigned short)f2bf(wout[k * F_ + f]);
            }
        }
        return;
    }

    // ---- in2f: 16 rows of ypre per block ----
    __shared__ unsigned short s_wt[128 * 136];   // win^T bf16, [f][k], pad 8

    const float4* win4 = (const float4*)win;
    for (int i = tid; i < 4096; i += 256) {
        const float4 v = win4[i];
        const int e = i * 4;
        const int k = e >> 7;
        const int f = e & 127;
        s_wt[(f + 0) * 136 + k] = (unsigned short)f2bf(v.x);
        s_wt[(f + 1) * 136 + k] = (unsigned short)f2bf(v.y);
        s_wt[(f + 2) * 136 + k] = (unsigned short)f2bf(v.z);
        s_wt[(f + 3) * 136 + k] = (unsigned short)f2bf(v.w);
    }
    __syncthreads();

    const int w = tid >> 6, l = tid & 63, quad = l >> 4, c0 = l & 15;
    const int row0 = bid * 16;

    short8 a[4];
    {
        const float* base = x + (size_t)(row0 + c0) * F_ + quad * 8;
        #pragma unroll
        for (int ks = 0; ks < 4; ++ks) {
            const float4 v0 = *(const float4*)(base + ks * 32);
            const float4 v1 = *(const float4*)(base + ks * 32 + 4);
            short8 t;
            t[0] = (short)f2bf(v0.x); t[1] = (short)f2bf(v0.y);
            t[2] = (short)f2bf(v0.z); t[3] = (short)f2bf(v0.w);
            t[4] = (short)f2bf(v1.x); t[5] = (short)f2bf(v1.y);
            t[6] = (short)f2bf(v1.z); t[7] = (short)f2bf(v1.w);
            a[ks] = t;
        }
    }

    floatx4 acc[2];
    acc[0] = (floatx4){0.f,0.f,0.f,0.f};
    acc[1] = (floatx4){0.f,0.f,0.f,0.f};
    #pragma unroll
    for (int t = 0; t < 2; ++t) {
        const int tf = w * 2 + t;
        #pragma unroll
        for (int ks = 0; ks < 4; ++ks) {
            const short8 bfrag = *(const short8*)
                &s_wt[(tf * 16 + c0) * 136 + ks * 32 + quad * 8];
            acc[t] = __builtin_amdgcn_mfma_f32_16x16x32_bf16(
                a[ks], bfrag, acc[t], 0, 0, 0);
        }
    }
    // permuted store: element (ro, col=tf*16+c0) -> ypre[ro*128 + c0*8 + tf]
    #pragma unroll
    for (int r = 0; r < 4; ++r) {
        const int ro = row0 + quad * 4 + r;
        const unsigned lo = f2bf(acc[0][r]);
        const unsigned hi = f2bf(acc[1][r]);
        *(unsigned*)&ypre[(size_t)ro * F_ + c0 * 8 + w * 2] = lo | (hi << 16);
    }
}

// ---------------------------------------------------------------------------
// K2: one block per (b,a). Filter net + cutoff + gather + aggregate.
// Wave w owns neighbor rows [w*16, w*16+16); no barrier until the reduction.
__global__ __launch_bounds__(256) void cfconv_kernel(
    const float* __restrict__ r_ij, const float* __restrict__ f_ij,
    const int*   __restrict__ nbrs, const float* __restrict__ mask,
    const float* __restrict__ fb1,  const float* __restrict__ fb2,
    const unsigned short* __restrict__ ypre,
    const unsigned short* __restrict__ fw1B,
    const unsigned short* __restrict__ fw2B,
    unsigned short* __restrict__ y_agg)
{
    __shared__ short s_h1[N_ * F_];       // 16 KB, XOR-chunk swizzle
    __shared__ float s_scale[N_];
    __shared__ int   s_nb[N_];
    __shared__ float s_red[4][F_];

    const int blk  = blockIdx.x;
    const int tid  = threadIdx.x;
    const int b    = blk >> 8;
    const int w    = tid >> 6;
    const int l    = tid & 63;
    const int quad = l >> 4;
    const int c0   = l & 15;

    if (l < 16) {
        const int n = w * 16 + l;
        const float r = r_ij[(size_t)blk * N_ + n];
        const float c = (r < 5.0f)
            ? 0.5f * (__cosf(r * 0.62831853071795865f) + 1.0f)
            : 0.0f;
        s_scale[n] = c * mask[(size_t)blk * N_ + n];
        s_nb[n]    = nbrs[(size_t)blk * N_ + n];
    }

    const short8* fw1B8 = (const short8*)fw1B;
    const short8* fw2B8 = (const short8*)fw2B;

    // ---- GEMM1: h1 = ssp(f_ij @ fw1 + fb1) ----
    short8 a1[2];
    {
        const float* base = f_ij + (size_t)blk * (N_ * G_)
                          + (size_t)(w * 16 + c0) * G_ + quad * 8;
        #pragma unroll
        for (int ks = 0; ks < 2; ++ks) {
            const float4 v0 = *(const float4*)(base + ks * 32);
            const float4 v1 = *(const float4*)(base + ks * 32 + 4);
            short8 a;
            a[0] = (short)f2bf(v0.x); a[1] = (short)f2bf(v0.y);
            a[2] = (short)f2bf(v0.z); a[3] = (short)f2bf(v0.w);
            a[4] = (short)f2bf(v1.x); a[5] = (short)f2bf(v1.y);
            a[6] = (short)f2bf(v1.z); a[7] = (short)f2bf(v1.w);
            a1[ks] = a;
        }
    }
    floatx4 acc1[8];
    #pragma unroll
    for (int tf = 0; tf < 8; ++tf) acc1[tf] = (floatx4){0.f,0.f,0.f,0.f};
    #pragma unroll
    for (int ks = 0; ks < 2; ++ks)
        #pragma unroll
        for (int tf = 0; tf < 8; ++tf)
            acc1[tf] = __builtin_amdgcn_mfma_f32_16x16x32_bf16(
                a1[ks], fw1B8[(tf * 2 + ks) * 64 + l], acc1[tf], 0, 0, 0);

    #pragma unroll
    for (int tf = 0; tf < 8; ++tf) {
        const float bias  = fb1[tf * 16 + c0];
        const int   chunk = tf * 2 + (c0 >> 3);
        const int   o     = c0 & 7;
        #pragma unroll
        for (int r = 0; r < 4; ++r) {
            const int row_l = quad * 4 + r;
            const float v = ssp(acc1[tf][r] + bias);
            s_h1[(w * 16 + row_l) * F_ + ((chunk ^ row_l) * 8) + o] =
                (short)f2bf(v);
        }
    }

    // ---- GEMM2 A-frags from LDS + prefetch permuted gather rows ----
    short8 a2[4];
    #pragma unroll
    for (int ks = 0; ks < 4; ++ks)
        a2[ks] = *(const short8*)&s_h1[(w * 16 + c0) * F_
                                       + (((ks * 4 + quad) ^ c0) * 8)];

    float scl[4];
    uint4 yv[4];
    #pragma unroll
    for (int r = 0; r < 4; ++r) {
        const int n = w * 16 + quad * 4 + r;
        scl[r] = s_scale[n];
        yv[r] = *(const uint4*)&ypre[(size_t)(b * A_ + s_nb[n]) * F_ + c0 * 8];
    }

    floatx4 acc2[8];
    #pragma unroll
    for (int tf = 0; tf < 8; ++tf) acc2[tf] = (floatx4){0.f,0.f,0.f,0.f};
    #pragma unroll
    for (int ks = 0; ks < 4; ++ks)
        #pragma unroll
        for (int tf = 0; tf < 8; ++tf)
            acc2[tf] = __builtin_amdgcn_mfma_f32_16x16x32_bf16(
                a2[ks], fw2B8[(tf * 4 + ks) * 64 + l], acc2[tf], 0, 0, 0);

    // ---- aggregate: part[f'] += (W+fb2)*scale * y_nbh[f'] ----
    float part[8];
    #pragma unroll
    for (int tf = 0; tf < 8; ++tf) part[tf] = 0.0f;
    #pragma unroll
    for (int r = 0; r < 4; ++r) {
        const unsigned d0 = yv[r].x, d1 = yv[r].y, d2 = yv[r].z, d3 = yv[r].w;
        part[0] = fmaf((acc2[0][r] + fb2[0*16+c0]) * scl[r], bf2f_lo(d0), part[0]);
        part[1] = fmaf((acc2[1][r] + fb2[1*16+c0]) * scl[r], bf2f_hi(d0), part[1]);
        part[2] = fmaf((acc2[2][r] + fb2[2*16+c0]) * scl[r], bf2f_lo(d1), part[2]);
        part[3] = fmaf((acc2[3][r] + fb2[3*16+c0]) * scl[r], bf2f_hi(d1), part[3]);
        part[4] = fmaf((acc2[4][r] + fb2[4*16+c0]) * scl[r], bf2f_lo(d2), part[4]);
        part[5] = fmaf((acc2[5][r] + fb2[5*16+c0]) * scl[r], bf2f_hi(d2), part[5]);
        part[6] = fmaf((acc2[6][r] + fb2[6*16+c0]) * scl[r], bf2f_lo(d3), part[6]);
        part[7] = fmaf((acc2[7][r] + fb2[7*16+c0]) * scl[r], bf2f_hi(d3), part[7]);
    }

    #pragma unroll
    for (int tf = 0; tf < 8; ++tf) {
        part[tf] += __shfl_xor(part[tf], 16, 64);
        part[tf] += __shfl_xor(part[tf], 32, 64);
    }
    if (l < 16) {
        #pragma unroll
        for (int tf = 0; tf < 8; ++tf)
            s_red[w][tf * 16 + l] = part[tf];
    }
    __syncthreads();

    if (tid < F_) {
        const float v = s_red[0][tid] + s_red[1][tid]
                      + s_red[2][tid] + s_red[3][tid];
        y_agg[(size_t)blk * F_ + tid] = (unsigned short)f2bf(v);
    }
}

// ---------------------------------------------------------------------------
// K3: out = ssp(y_agg @ w_f2out + b_f2out). 64 blocks x 64 rows.
__global__ __launch_bounds__(256) void f2out_kernel(
    const unsigned short* __restrict__ y_agg,
    const unsigned short* __restrict__ woutB,
    const float* __restrict__ bias, float* __restrict__ out)
{
    const int tid = threadIdx.x;
    const int w = tid >> 6, l = tid & 63, quad = l >> 4, c0 = l & 15;
    const int row = blockIdx.x * 64 + w * 16 + c0;

    short8 a[4];
    #pragma unroll
    for (int ks = 0; ks < 4; ++ks)
        a[ks] = *(const short8*)&y_agg[(size_t)row * F_ + ks * 32 + quad * 8];

    const short8* W8 = (const short8*)woutB;
    floatx4 acc[8];
    #pragma unroll
    for (int tf = 0; tf < 8; ++tf) acc[tf] = (floatx4){0.f,0.f,0.f,0.f};
    #pragma unroll
    for (int ks = 0; ks < 4; ++ks)
        #pragma unroll
        for (int tf = 0; tf < 8; ++tf)
            acc[tf] = __builtin_amdgcn_mfma_f32_16x16x32_bf16(
                a[ks], W8[(tf * 4 + ks) * 64 + l], acc[tf], 0, 0, 0);

    #pragma unroll
    for (int tf = 0; tf < 8; ++tf) {
        const float bs = bias[tf * 16 + c0];
        #pragma unroll
        for (int r = 0; r < 4; ++r) {
            const int ro = blockIdx.x * 64 + w * 16 + quad * 4 + r;
            out[(size_t)ro * F_ + tf * 16 + c0] = ssp(acc[tf][r] + bs);
        }
    }
}

// ---------------------------------------------------------------------------
extern "C" void kernel_launch(void* const* d_in, const int* in_sizes, int n_in,
                              void* d_out, int out_size, void* d_ws, size_t ws_size,
                              hipStream_t stream) {
    const float* x        = (const float*)d_in[0];
    const float* r_ij     = (const float*)d_in[1];
    const float* f_ij     = (const float*)d_in[2];
    const int*   nbrs     = (const int*)  d_in[3];
    const float* mask     = (const float*)d_in[4];
    const float* fw1      = (const float*)d_in[5];
    const float* fb1      = (const float*)d_in[6];
    const float* fw2      = (const float*)d_in[7];
    const float* fb2      = (const float*)d_in[8];
    const float* w_in2f   = (const float*)d_in[9];
    const float* w_f2out  = (const float*)d_in[10];
    const float* b_f2out  = (const float*)d_in[11];
    float* out = (float*)d_out;

    // ws (shorts): ypre | fw1B | fw2B | woutB | y_agg
    unsigned short* ypre  = (unsigned short*)d_ws;
    unsigned short* fw1B  = ypre  + (size_t)B_ * A_ * F_;   // 524288
    unsigned short* fw2B  = fw1B  + 8192;
    unsigned short* woutB = fw2B  + 16384;
    unsigned short* y_agg = woutB + 16384;

    k1_prep_in2f<<<296, 256, 0, stream>>>(
        x, w_in2f, fw1, fw2, w_f2out, ypre, fw1B, fw2B, woutB);
    cfconv_kernel<<<B_ * A_, 256, 0, stream>>>(
        r_ij, f_ij, nbrs, mask, fb1, fb2, ypre, fw1B, fw2B, y_agg);
    f2out_kernel<<<B_ * A_ / 64, 256, 0, stream>>>(y_agg, woutB, b_f2out, out);
}